// Round 1
// baseline (543.337 us; speedup 1.0000x reference)
//
#include <hip/hip_runtime.h>
#include <math.h>

#define LEAKY(v) ((v) > 0.0f ? (v) : 0.01f * (v))

__device__ __forceinline__ float sigmoidf_(float z) {
    return 1.0f / (1.0f + __expf(-z));
}

// One thread per point. All small matvecs fully unrolled into registers.
// FC weights are read with wave-uniform addresses (no threadIdx dependence)
// -> AMDGPU backend scalarizes them to s_load (constant-cache path), so the
// VALU only does the FMAs. Grid gathers are float4 (rows are 32 floats,
// 128B-aligned).
__global__ __launch_bounds__(256) void gridnet_fwd(
    const float2* __restrict__ pos, const float2* __restrict__ dir_,
    const float* __restrict__ pos_grid, const float* __restrict__ dir_grid,
    const float* __restrict__ enc_w1, const float* __restrict__ enc_b1,
    const float* __restrict__ enc_w2, const float* __restrict__ enc_b2,
    const float* __restrict__ fc_w1, const float* __restrict__ fc_b1,
    const float* __restrict__ fc_w2, const float* __restrict__ fc_b2,
    const float* __restrict__ fc_w3, const float* __restrict__ fc_b3,
    const float* __restrict__ fc_w4, const float* __restrict__ fc_b4,
    float* __restrict__ out, int n)
{
    int i = blockIdx.x * blockDim.x + threadIdx.x;
    if (i >= n) return;

    float feat[64];

    #pragma unroll
    for (int pass = 0; pass < 2; ++pass) {
        float2 xy = (pass == 0) ? pos[i] : dir_[i];
        const float* grid = (pass == 0) ? pos_grid : dir_grid;

        // encoder: h = tanh(xy @ enc_w1 + enc_b1)  (enc_w1 is [2,4] row-major)
        float h[4];
        #pragma unroll
        for (int k = 0; k < 4; ++k)
            h[k] = tanhf(xy.x * enc_w1[k] + xy.y * enc_w1[4 + k] + enc_b1[k]);
        // e = sigmoid(h @ enc_w2 + enc_b2), only cols 0,1 used (enc_w2 is [4,3])
        float e0 = enc_b2[0], e1 = enc_b2[1];
        #pragma unroll
        for (int k = 0; k < 4; ++k) {
            e0 += h[k] * enc_w2[3 * k + 0];
            e1 += h[k] * enc_w2[3 * k + 1];
        }
        float x = sigmoidf_(e0) * 255.0f;   // W = GW-1 = 255
        float y = sigmoidf_(e1) * 255.0f;   // H = GH-1 = 255

        int x0 = (int)x, y0 = (int)y;       // trunc == floor (x,y > 0)
        float xf = x - (float)x0, yf = y - (float)y0;
        int x1 = min(x0 + 1, 255), y1 = min(y0 + 1, 255);

        const float4* tl = (const float4*)(grid + ((y0 << 8) + x0) * 32);
        const float4* tr = (const float4*)(grid + ((y0 << 8) + x1) * 32);
        const float4* bl = (const float4*)(grid + ((y1 << 8) + x0) * 32);
        const float4* br = (const float4*)(grid + ((y1 << 8) + x1) * 32);

        float* f = feat + pass * 32;
        float oxf = 1.0f - xf, oyf = 1.0f - yf;
        #pragma unroll
        for (int c = 0; c < 8; ++c) {
            float4 a = tl[c], b4 = tr[c], c4 = bl[c], d4 = br[c];
            f[4 * c + 0] = oyf * (oxf * a.x + xf * b4.x) + yf * (oxf * c4.x + xf * d4.x);
            f[4 * c + 1] = oyf * (oxf * a.y + xf * b4.y) + yf * (oxf * c4.y + xf * d4.y);
            f[4 * c + 2] = oyf * (oxf * a.z + xf * b4.z) + yf * (oxf * c4.z + xf * d4.z);
            f[4 * c + 3] = oyf * (oxf * a.w + xf * b4.w) + yf * (oxf * c4.w + xf * d4.w);
        }
    }

    // fc1: 64 -> 64, leaky relu. fc_w1 is [64,64] row-major (in, out).
    float h1[64];
    #pragma unroll
    for (int j = 0; j < 64; ++j) h1[j] = fc_b1[j];
    #pragma unroll
    for (int k = 0; k < 64; ++k) {
        float xv = feat[k];
        #pragma unroll
        for (int j = 0; j < 64; ++j)
            h1[j] = fmaf(xv, fc_w1[(k << 6) + j], h1[j]);
    }
    #pragma unroll
    for (int j = 0; j < 64; ++j) h1[j] = LEAKY(h1[j]);

    // fc2: 64 -> 16
    float h2[16];
    #pragma unroll
    for (int j = 0; j < 16; ++j) h2[j] = fc_b2[j];
    #pragma unroll
    for (int k = 0; k < 64; ++k) {
        float xv = h1[k];
        #pragma unroll
        for (int j = 0; j < 16; ++j)
            h2[j] = fmaf(xv, fc_w2[(k << 4) + j], h2[j]);
    }
    #pragma unroll
    for (int j = 0; j < 16; ++j) h2[j] = LEAKY(h2[j]);

    // fc3: 16 -> 8
    float h3[8];
    #pragma unroll
    for (int j = 0; j < 8; ++j) h3[j] = fc_b3[j];
    #pragma unroll
    for (int k = 0; k < 16; ++k) {
        float xv = h2[k];
        #pragma unroll
        for (int j = 0; j < 8; ++j)
            h3[j] = fmaf(xv, fc_w3[(k << 3) + j], h3[j]);
    }
    #pragma unroll
    for (int j = 0; j < 8; ++j) h3[j] = LEAKY(h3[j]);

    // fc4: 8 -> 3, leaky, sigmoid*255
    float o[3];
    #pragma unroll
    for (int j = 0; j < 3; ++j) o[j] = fc_b4[j];
    #pragma unroll
    for (int k = 0; k < 8; ++k) {
        float xv = h3[k];
        #pragma unroll
        for (int j = 0; j < 3; ++j)
            o[j] = fmaf(xv, fc_w4[3 * k + j], o[j]);
    }
    #pragma unroll
    for (int j = 0; j < 3; ++j) {
        float v = LEAKY(o[j]);
        out[3 * i + j] = sigmoidf_(v) * 255.0f;
    }
}

extern "C" void kernel_launch(void* const* d_in, const int* in_sizes, int n_in,
                              void* d_out, int out_size, void* d_ws, size_t ws_size,
                              hipStream_t stream) {
    int n = in_sizes[0] / 2;  // pos is [N,2]
    dim3 block(256);
    dim3 grid((n + 255) / 256);
    gridnet_fwd<<<grid, block, 0, stream>>>(
        (const float2*)d_in[0], (const float2*)d_in[1],
        (const float*)d_in[2], (const float*)d_in[3],
        (const float*)d_in[4], (const float*)d_in[5],
        (const float*)d_in[6], (const float*)d_in[7],
        (const float*)d_in[8], (const float*)d_in[9],
        (const float*)d_in[10], (const float*)d_in[11],
        (const float*)d_in[12], (const float*)d_in[13],
        (const float*)d_in[14], (const float*)d_in[15],
        (float*)d_out, n);
}

// Round 2
// 284.954 us; speedup vs baseline: 1.9068x; 1.9068x over previous
//
#include <hip/hip_runtime.h>
#include <math.h>

typedef __attribute__((ext_vector_type(8))) __bf16 bf16x8;
typedef __attribute__((ext_vector_type(4))) __bf16 bf16x4;
typedef __attribute__((ext_vector_type(4))) float floatx4;

#define LEAKY(v) ((v) > 0.0f ? (v) : 0.01f * (v))

__device__ __forceinline__ float fast_rcp(float x) { return __builtin_amdgcn_rcpf(x); }
__device__ __forceinline__ float sigmoidf_(float z) { return fast_rcp(1.0f + __expf(-z)); }
__device__ __forceinline__ float fast_tanh(float z) {
    float e = __expf(2.0f * z);
    return 1.0f - 2.0f * fast_rcp(e + 1.0f);
}

// ---- grid fp32 -> bf16 conversion into workspace (runs every launch) ----
__global__ void convert_grids(const float* __restrict__ g0, const float* __restrict__ g1,
                              __bf16* __restrict__ o0, __bf16* __restrict__ o1, int elems) {
    int i = blockIdx.x * blockDim.x + threadIdx.x;
    int nvec = elems >> 2;
    if (i < nvec) {
        float4 v = ((const float4*)g0)[i];
        bf16x4 r = { (__bf16)v.x, (__bf16)v.y, (__bf16)v.z, (__bf16)v.w };
        ((bf16x4*)o0)[i] = r;
    } else if (i < 2 * nvec) {
        int j = i - nvec;
        float4 v = ((const float4*)g1)[j];
        bf16x4 r = { (__bf16)v.x, (__bf16)v.y, (__bf16)v.z, (__bf16)v.w };
        ((bf16x4*)o1)[j] = r;
    }
}

// Per-wave: 64 points. Encoder+gather per-lane (lane=point), feats -> LDS bf16,
// fc1 (64x64) and fc2 (64x16) via mfma_f32_16x16x32_bf16, fc3/fc4 per-lane VALU.
// LDS layouts: X/h1 [pt][feat] stride 80 bf16 (16B aligned rows, conflict-balanced),
// W1 [out][in] stride 72, W2 [out][in] stride 72.
// Intra-wave LDS exchanges fenced with s_waitcnt lgkmcnt(0) (wave-synchronous, no barrier).
template<bool BF16G>
__global__ __launch_bounds__(256) void gridnet_fwd(
    const float2* __restrict__ pos, const float2* __restrict__ dir_,
    const float* __restrict__ pos_gridf, const float* __restrict__ dir_gridf,
    const __bf16* __restrict__ pos_gridb, const __bf16* __restrict__ dir_gridb,
    const float* __restrict__ enc_w1, const float* __restrict__ enc_b1,
    const float* __restrict__ enc_w2, const float* __restrict__ enc_b2,
    const float* __restrict__ fc_w1, const float* __restrict__ fc_b1,
    const float* __restrict__ fc_w2, const float* __restrict__ fc_b2,
    const float* __restrict__ fc_w3, const float* __restrict__ fc_b3,
    const float* __restrict__ fc_w4, const float* __restrict__ fc_b4,
    float* __restrict__ out, int n)
{
    __shared__ __align__(16) __bf16 smem[4*64*80 + 64*72 + 16*72];
    __shared__ float b1lds[64];
    __shared__ float b2lds[16];

    const int tid  = threadIdx.x;
    const int lane = tid & 63;
    const int wid  = tid >> 6;
    const int quad = lane >> 4;
    const int l15  = lane & 15;

    __bf16* W1p = smem + 4*64*80;
    __bf16* W2p = W1p + 64*72;
    __bf16* Xw  = smem + wid*64*80;

    // one-time weight staging (bf16, [out][in] layout, padded stride 72)
    for (int idx = tid; idx < 4096; idx += 256) {
        int k = idx >> 6, nn = idx & 63;
        W1p[nn*72 + k] = (__bf16)fc_w1[idx];
    }
    for (int idx = tid; idx < 1024; idx += 256) {
        int k = idx >> 4, nn = idx & 15;
        W2p[nn*72 + k] = (__bf16)fc_w2[idx];
    }
    if (tid < 64) b1lds[tid] = fc_b1[tid];
    if (tid < 16) b2lds[tid] = fc_b2[tid];
    __syncthreads();

    float b1r[4];
    #pragma unroll
    for (int nt = 0; nt < 4; ++nt) b1r[nt] = b1lds[nt*16 + l15];
    float b2r = b2lds[l15];

    int nb = (n + 255) >> 8;
    for (int batch = blockIdx.x; batch < nb; batch += (int)gridDim.x) {
        int i  = batch*256 + wid*64 + lane;
        int ic = min(i, n - 1);

        // ---- encoder + bilinear gather; feats written to LDS as bf16 ----
        #pragma unroll
        for (int pass = 0; pass < 2; ++pass) {
            float2 xy = (pass == 0) ? pos[ic] : dir_[ic];
            float hh[4];
            #pragma unroll
            for (int k2 = 0; k2 < 4; ++k2)
                hh[k2] = fast_tanh(xy.x*enc_w1[k2] + xy.y*enc_w1[4+k2] + enc_b1[k2]);
            float e0 = enc_b2[0], e1 = enc_b2[1];
            #pragma unroll
            for (int k2 = 0; k2 < 4; ++k2) {
                e0 += hh[k2]*enc_w2[3*k2 + 0];
                e1 += hh[k2]*enc_w2[3*k2 + 1];
            }
            float x = sigmoidf_(e0) * 255.0f;
            float y = sigmoidf_(e1) * 255.0f;
            int x0 = (int)x, y0 = (int)y;
            float xf = x - (float)x0, yf = y - (float)y0;
            int x1 = min(x0 + 1, 255), y1 = min(y0 + 1, 255);
            float oxf = 1.0f - xf, oyf = 1.0f - yf;
            float wtl = oyf*oxf, wtr = oyf*xf, wbl = yf*oxf, wbr = yf*xf;
            int ctl = ((y0 << 8) + x0) << 5, ctr = ((y0 << 8) + x1) << 5;
            int cbl = ((y1 << 8) + x0) << 5, cbr = ((y1 << 8) + x1) << 5;

            if (BF16G) {
                const __bf16* g = (pass == 0) ? pos_gridb : dir_gridb;
                #pragma unroll
                for (int c = 0; c < 4; ++c) {
                    bf16x8 a  = *(const bf16x8*)(g + ctl + c*8);
                    bf16x8 b  = *(const bf16x8*)(g + ctr + c*8);
                    bf16x8 cc = *(const bf16x8*)(g + cbl + c*8);
                    bf16x8 d  = *(const bf16x8*)(g + cbr + c*8);
                    bf16x8 r;
                    #pragma unroll
                    for (int j = 0; j < 8; ++j) {
                        float v = wtl*(float)a[j] + wtr*(float)b[j] + wbl*(float)cc[j] + wbr*(float)d[j];
                        r[j] = (__bf16)v;
                    }
                    *(bf16x8*)(Xw + lane*80 + (pass*4 + c)*8) = r;
                }
            } else {
                const float* g = (pass == 0) ? pos_gridf : dir_gridf;
                #pragma unroll
                for (int c = 0; c < 4; ++c) {
                    float fa[8], fb[8], fcc[8], fd[8];
                    *(float4*)(fa)     = *(const float4*)(g + ctl + c*8);
                    *(float4*)(fa + 4) = *(const float4*)(g + ctl + c*8 + 4);
                    *(float4*)(fb)     = *(const float4*)(g + ctr + c*8);
                    *(float4*)(fb + 4) = *(const float4*)(g + ctr + c*8 + 4);
                    *(float4*)(fcc)    = *(const float4*)(g + cbl + c*8);
                    *(float4*)(fcc + 4)= *(const float4*)(g + cbl + c*8 + 4);
                    *(float4*)(fd)     = *(const float4*)(g + cbr + c*8);
                    *(float4*)(fd + 4) = *(const float4*)(g + cbr + c*8 + 4);
                    bf16x8 r;
                    #pragma unroll
                    for (int j = 0; j < 8; ++j) {
                        float v = wtl*fa[j] + wtr*fb[j] + wbl*fcc[j] + wbr*fd[j];
                        r[j] = (__bf16)v;
                    }
                    *(bf16x8*)(Xw + lane*80 + (pass*4 + c)*8) = r;
                }
            }
        }

        // all lanes' feats visible before cross-lane A-fragment reads
        __asm__ volatile("s_waitcnt lgkmcnt(0)" ::: "memory");

        // ---- fc1: [64pt x 64] @ [64 x 64] via 32 MFMAs ----
        floatx4 acc[4][4];
        #pragma unroll
        for (int nt = 0; nt < 4; ++nt) {
            float b = b1r[nt];
            #pragma unroll
            for (int mt = 0; mt < 4; ++mt) acc[mt][nt] = (floatx4){b, b, b, b};
        }
        #pragma unroll
        for (int ks = 0; ks < 2; ++ks) {
            bf16x8 af[4], bfr[4];
            #pragma unroll
            for (int mt = 0; mt < 4; ++mt)
                af[mt] = *(const bf16x8*)(Xw + (mt*16 + l15)*80 + ks*32 + quad*8);
            #pragma unroll
            for (int nt = 0; nt < 4; ++nt)
                bfr[nt] = *(const bf16x8*)(W1p + (nt*16 + l15)*72 + ks*32 + quad*8);
            #pragma unroll
            for (int mt = 0; mt < 4; ++mt)
                #pragma unroll
                for (int nt = 0; nt < 4; ++nt)
                    acc[mt][nt] = __builtin_amdgcn_mfma_f32_16x16x32_bf16(af[mt], bfr[nt], acc[mt][nt], 0, 0, 0);
        }

        // leaky-relu + write h1 back into Xw (bf16). C/D: col=l15(out), row=quad*4+reg(pt).
        #pragma unroll
        for (int mt = 0; mt < 4; ++mt)
            #pragma unroll
            for (int nt = 0; nt < 4; ++nt)
                #pragma unroll
                for (int r = 0; r < 4; ++r) {
                    float v = acc[mt][nt][r];
                    v = LEAKY(v);
                    Xw[(mt*16 + quad*4 + r)*80 + nt*16 + l15] = (__bf16)v;
                }
        __asm__ volatile("s_waitcnt lgkmcnt(0)" ::: "memory");

        // ---- fc2: [64pt x 64] @ [64 x 16] via 8 MFMAs ----
        floatx4 acc2[4];
        #pragma unroll
        for (int mt = 0; mt < 4; ++mt) acc2[mt] = (floatx4){b2r, b2r, b2r, b2r};
        #pragma unroll
        for (int ks = 0; ks < 2; ++ks) {
            bf16x8 wf = *(const bf16x8*)(W2p + l15*72 + ks*32 + quad*8);
            #pragma unroll
            for (int mt = 0; mt < 4; ++mt) {
                bf16x8 a2 = *(const bf16x8*)(Xw + (mt*16 + l15)*80 + ks*32 + quad*8);
                acc2[mt] = __builtin_amdgcn_mfma_f32_16x16x32_bf16(a2, wf, acc2[mt], 0, 0, 0);
            }
        }

        // h2 -> LDS fp32 [pt][16], then each lane reads its own point's 16 values
        float* H2f = (float*)Xw;
        #pragma unroll
        for (int mt = 0; mt < 4; ++mt)
            #pragma unroll
            for (int r = 0; r < 4; ++r) {
                float v = acc2[mt][r];
                v = LEAKY(v);
                H2f[(mt*16 + quad*4 + r)*16 + l15] = v;
            }
        __asm__ volatile("s_waitcnt lgkmcnt(0)" ::: "memory");

        float h2[16];
        #pragma unroll
        for (int c = 0; c < 4; ++c) {
            floatx4 v = *(const floatx4*)(H2f + lane*16 + c*4);
            h2[4*c + 0] = v[0]; h2[4*c + 1] = v[1];
            h2[4*c + 2] = v[2]; h2[4*c + 3] = v[3];
        }

        // ---- fc3 / fc4 per-lane (152 FMAs), sigmoid, store ----
        float h3[8];
        #pragma unroll
        for (int j = 0; j < 8; ++j) h3[j] = fc_b3[j];
        #pragma unroll
        for (int k2 = 0; k2 < 16; ++k2) {
            float xv = h2[k2];
            #pragma unroll
            for (int j = 0; j < 8; ++j) h3[j] = fmaf(xv, fc_w3[(k2 << 3) + j], h3[j]);
        }
        #pragma unroll
        for (int j = 0; j < 8; ++j) h3[j] = LEAKY(h3[j]);

        float o[3];
        #pragma unroll
        for (int j = 0; j < 3; ++j) o[j] = fc_b4[j];
        #pragma unroll
        for (int k2 = 0; k2 < 8; ++k2) {
            float xv = h3[k2];
            #pragma unroll
            for (int j = 0; j < 3; ++j) o[j] = fmaf(xv, fc_w4[3*k2 + j], o[j]);
        }
        if (i < n) {
            #pragma unroll
            for (int j = 0; j < 3; ++j)
                out[3*i + j] = sigmoidf_(LEAKY(o[j])) * 255.0f;
        }
    }
}

extern "C" void kernel_launch(void* const* d_in, const int* in_sizes, int n_in,
                              void* d_out, int out_size, void* d_ws, size_t ws_size,
                              hipStream_t stream) {
    int n = in_sizes[0] / 2;  // pos is [N,2]
    const int GELEMS = 256 * 256 * 32;  // elements per grid
    bool use_bf16 = ws_size >= (size_t)(2 * GELEMS * sizeof(__bf16));
    __bf16* g0 = (__bf16*)d_ws;
    __bf16* g1 = g0 + GELEMS;

    if (use_bf16) {
        int total = 2 * (GELEMS / 4);
        convert_grids<<<(total + 255) / 256, 256, 0, stream>>>(
            (const float*)d_in[2], (const float*)d_in[3], g0, g1, GELEMS);
    }

    int nb = (n + 255) / 256;
    int blocks = nb < 2048 ? nb : 2048;
    if (use_bf16) {
        gridnet_fwd<true><<<blocks, 256, 0, stream>>>(
            (const float2*)d_in[0], (const float2*)d_in[1],
            (const float*)d_in[2], (const float*)d_in[3], g0, g1,
            (const float*)d_in[4], (const float*)d_in[5],
            (const float*)d_in[6], (const float*)d_in[7],
            (const float*)d_in[8], (const float*)d_in[9],
            (const float*)d_in[10], (const float*)d_in[11],
            (const float*)d_in[12], (const float*)d_in[13],
            (const float*)d_in[14], (const float*)d_in[15],
            (float*)d_out, n);
    } else {
        gridnet_fwd<false><<<blocks, 256, 0, stream>>>(
            (const float2*)d_in[0], (const float2*)d_in[1],
            (const float*)d_in[2], (const float*)d_in[3], g0, g1,
            (const float*)d_in[4], (const float*)d_in[5],
            (const float*)d_in[6], (const float*)d_in[7],
            (const float*)d_in[8], (const float*)d_in[9],
            (const float*)d_in[10], (const float*)d_in[11],
            (const float*)d_in[12], (const float*)d_in[13],
            (const float*)d_in[14], (const float*)d_in[15],
            (float*)d_out, n);
    }
}